// Round 12
// baseline (153.960 us; speedup 1.0000x reference)
//
#include <hip/hip_runtime.h>
#include <math.h>

#define B 8
#define C 3
#define H 1024
#define W 1024
#define L 1024
#define D 512
#define DH 128
#define NPIX (H * W)
#define NOISY_ELEMS (B * C * NPIX) // 25165824
#define TH 32                      // rows per strip in final kernel
#define RPB 8                      // rows per block in hblur
#define LROW 1056                  // padded LDS row

typedef float vf2 __attribute__((ext_vector_type(2)));
typedef float vf4 __attribute__((ext_vector_type(4)));
typedef unsigned short us4 __attribute__((ext_vector_type(4)));

struct BlurW { float w[21]; };

static __device__ __forceinline__ unsigned short f2bf(float f) {
    unsigned u = __float_as_uint(f);
    u += 0x7FFFu + ((u >> 16) & 1u);       // round-to-nearest-even
    return (unsigned short)(u >> 16);
}

// ---- kernel A: hblur (bf16 hmask) + colsum + counter-elected head MLP ------
// blocks [0, 1024): 8 mask rows each, staged in LDS, vf4 in, bf16x4 out.
// blocks [1024, 1280): colsum 32 rows of one batch; last block per batch
// (device-scope counter) runs the head MLP inline.
__global__ __launch_bounds__(256) void produce_kernel(
        const float* __restrict__ mask, unsigned short* __restrict__ hmask,
        const float* __restrict__ feat, float* __restrict__ partial,
        int* __restrict__ counters,
        const float* __restrict__ W1, const float* __restrict__ b1,
        const float* __restrict__ ln_g, const float* __restrict__ ln_b,
        const float* __restrict__ W2, const float* __restrict__ b2,
        float* __restrict__ ab, float* __restrict__ out_tail, BlurW kw) {
    int wgid = blockIdx.x;
    int t = threadIdx.x;             // 256

    if (wgid < 1024) {
        __shared__ float Ls[RPB][LROW];  // data at [12..12+W-1], zero halo 10/side
        size_t row0 = (size_t)wgid * RPB;
        const float* src = mask + row0 * W;
        #pragma unroll
        for (int r = 0; r < RPB; ++r) {
            vf4 v = *((const vf4*)(src + (size_t)r * W) + t);
            *(vf4*)&Ls[r][12 + 4 * t] = v;
        }
        if (t < RPB * 10) {
            int r = t / 10, i = t - 10 * r;
            Ls[r][2 + i] = 0.f;
            Ls[r][12 + W + i] = 0.f;
        }
        __syncthreads();
        unsigned short* dst = hmask + row0 * W;
        #pragma unroll
        for (int r = 0; r < RPB; ++r) {
            float v[28];
            #pragma unroll
            for (int j = 0; j < 7; ++j) {
                vf4 q = *(const vf4*)&Ls[r][4 * t + 4 * j];
                v[4 * j] = q.x; v[4 * j + 1] = q.y; v[4 * j + 2] = q.z; v[4 * j + 3] = q.w;
            }
            us4 o;
            #pragma unroll
            for (int i = 0; i < 4; ++i) {
                float acc = 0.f;
                #pragma unroll
                for (int k = 0; k < 10; ++k)
                    acc = fmaf(kw.w[k], v[i + 2 + k] + v[i + 22 - k], acc);
                acc = fmaf(kw.w[10], v[i + 12], acc);
                o[i] = f2bf(acc);
            }
            *(us4*)(dst + (size_t)r * W + 4 * t) = o;   // plain: L2/L3-resident
        }
        return;
    }

    // ---------------- colsum branch ----------------
    int blk = wgid - 1024;           // 0..255
    int b = blk >> 5, chunk = blk & 31;
    int d4 = (t & 127) * 4;
    int half = t >> 7;
    {
        const float* base = feat + (size_t)b * (L * D)
                          + (size_t)(chunk * 32 + half * 16) * D + d4;
        vf4 s = {0.f, 0.f, 0.f, 0.f};
        #pragma unroll
        for (int ll = 0; ll < 16; ++ll) {
            vf4 v = *(const vf4*)(base + (size_t)ll * D);
            s.x += v.x; s.y += v.y; s.z += v.z; s.w += v.w;
        }
        *(vf4*)(partial + ((size_t)(b * 64 + chunk * 2 + half)) * 512 + d4) = s;
    }

    // elect last colsum block of this batch
    __threadfence();                 // release partial write
    __shared__ int winner;
    if (t == 0) winner = (atomicAdd(&counters[b], 1) == 31);
    __syncthreads();
    if (!winner) return;             // block-uniform
    __threadfence();                 // acquire other blocks' partials

    // ---------------- head MLP for batch b (256 threads) ----------------
    __shared__ float fm[D];
    __shared__ float red[DH];
    for (int d = t; d < D; d += 256) {
        float acc = 0.f;
        const float* p = partial + (size_t)b * 64 * 512 + d;
        for (int g = 0; g < 64; ++g) acc += p[g * 512];
        fm[d] = acc * (1.0f / (float)L);
    }
    __syncthreads();
    float h = 0.f;
    if (t < DH) {
        h = b1[t];
        const vf4* fm4 = (const vf4*)fm;
        #pragma unroll 8
        for (int q = 0; q < D / 4; ++q) {
            vf4 f = fm4[q];
            h = fmaf(f.x, W1[(4 * q + 0) * DH + t], h);
            h = fmaf(f.y, W1[(4 * q + 1) * DH + t], h);
            h = fmaf(f.z, W1[(4 * q + 2) * DH + t], h);
            h = fmaf(f.w, W1[(4 * q + 3) * DH + t], h);
        }
    }

    if (t < DH) red[t] = h;
    __syncthreads();
    for (int st = 64; st > 0; st >>= 1) { if (t < st) red[t] += red[t + st]; __syncthreads(); }
    float mu = red[0] * (1.f / (float)DH);
    __syncthreads();
    float hc = h - mu;
    if (t < DH) red[t] = hc * hc;
    __syncthreads();
    for (int st = 64; st > 0; st >>= 1) { if (t < st) red[t] += red[t + st]; __syncthreads(); }
    float var = red[0] * (1.f / (float)DH);
    __syncthreads();

    float hn = 0.f;
    if (t < DH) {
        hn = hc * rsqrtf(var + 1e-5f) * ln_g[t] + ln_b[t];
        hn = fmaxf(hn, 0.f);
    }

    if (t < DH) red[t] = hn * W2[t * 2 + 0];
    __syncthreads();
    for (int st = 64; st > 0; st >>= 1) { if (t < st) red[t] += red[t + st]; __syncthreads(); }
    float p0 = red[0];
    __syncthreads();
    if (t < DH) red[t] = hn * W2[t * 2 + 1];
    __syncthreads();
    for (int st = 64; st > 0; st >>= 1) { if (t < st) red[t] += red[t + st]; __syncthreads(); }
    float p1 = red[0];

    if (t == 0) {
        float a  = 0.00015f / (1.f + expf(-(p0 + b2[0])));
        float be = 0.00015f / (1.f + expf(-(p1 + b2[1])));
        ab[b] = a; ab[8 + b] = be;
        out_tail[b] = a; out_tail[8 + b] = be;
    }
}

// ---------------- kernel B: vertical blur + elementwise synth ---------------
// grid: B * 32 strips (TH=32) * 2 half-widths = 512 blocks, 256 threads.
// Thread t owns 2 adjacent columns (vf2). bf16 window (4B loads) unpacked to
// f32 regs; DYNAMIC outer loop + explicit window shift (all-literal indices,
// no giant unroll, no spill). Plain loads (L3-allocate), nt store only.
__global__ __launch_bounds__(256) void final_kernel(
        const float* __restrict__ x_bg, const float* __restrict__ noise,
        const unsigned short* __restrict__ hmask, const float* __restrict__ ab,
        float* __restrict__ out, BlurW kw) {
    int blk = blockIdx.x;            // 0..511
    int b   = blk >> 6;              // 64 blocks per batch
    int rem = blk & 63;
    int s   = rem >> 1;              // strip 0..31
    int wj  = rem & 1;
    int h0  = s * TH;
    int t   = threadIdx.x;           // 0..255
    int x0  = wj * 512 + 2 * t;      // column pair base

    const unsigned short* hmb = hmask + (size_t)b * NPIX + x0;
    const vf2 zero2 = {0.f, 0.f};

    vf2 win[21];
    #pragma unroll
    for (int k = 0; k < 21; ++k) {
        int hy = h0 - 10 + k;
        if (hy >= 0) {               // hy < H always true in prologue
            unsigned u = *(const unsigned*)(hmb + (size_t)hy * W);
            win[k].x = __uint_as_float(u << 16);
            win[k].y = __uint_as_float(u & 0xFFFF0000u);
        } else win[k] = zero2;
    }

    float alpha = ab[b], beta = ab[8 + b];

    for (int r = 0; r < TH; ++r) {
        // symmetric vblur: current row's taps are exactly win[0..20]
        float mx = 0.f, my = 0.f;
        #pragma unroll
        for (int k = 0; k < 10; ++k) {
            float wk = kw.w[k];
            mx = fmaf(wk, win[k].x + win[20 - k].x, mx);
            my = fmaf(wk, win[k].y + win[20 - k].y, my);
        }
        mx = fmaf(kw.w[10], win[10].x, mx);
        my = fmaf(kw.w[10], win[10].y, my);

        int h = h0 + r;
        #pragma unroll
        for (int c = 0; c < C; ++c) {
            size_t idx = (((size_t)(b * C + c) * H) + h) * W + x0;
            vf2 x  = *(const vf2*)(x_bg + idx);
            vf2 nz = *(const vf2*)(noise + idx);
            vf2 o;
            float sgx = sqrtf(fmaxf(fmaf(alpha, x.x, beta), 1e-7f));
            float sgy = sqrtf(fmaxf(fmaf(alpha, x.y, beta), 1e-7f));
            o.x = fmaf(1.5f * nz.x * sgx, mx, x.x);
            o.y = fmaf(1.5f * nz.y * sgy, my, x.y);
            __builtin_nontemporal_store(o, (vf2*)(out + idx));
        }

        // shift window, load row h+11
        #pragma unroll
        for (int i = 0; i < 20; ++i) win[i] = win[i + 1];
        {
            int hy = h + 11;
            if (hy < H) {
                unsigned u = *(const unsigned*)(hmb + (size_t)hy * W);
                win[20].x = __uint_as_float(u << 16);
                win[20].y = __uint_as_float(u & 0xFFFF0000u);
            } else win[20] = zero2;
        }
    }
}

extern "C" void kernel_launch(void* const* d_in, const int* in_sizes, int n_in,
                              void* d_out, int out_size, void* d_ws, size_t ws_size,
                              hipStream_t stream) {
    const float* x_bg = (const float*)d_in[0];
    const float* feat = (const float*)d_in[1];
    const float* mask = (const float*)d_in[2];
    const float* noise = (const float*)d_in[3];
    const float* W1 = (const float*)d_in[4];
    const float* b1 = (const float*)d_in[5];
    const float* ln_g = (const float*)d_in[6];
    const float* ln_b = (const float*)d_in[7];
    const float* W2 = (const float*)d_in[8];
    const float* b2 = (const float*)d_in[9];
    float* out = (float*)d_out;

    // ws layout: [0, 262144) partial colsums (f32) | [262144,+16) ab (f32)
    //            | [+32, +8 ints) counters | hmask bf16 (B*NPIX ushorts)
    float* ws_f = (float*)d_ws;
    float* partial = ws_f;                       // 8*64*512 = 262144 floats
    float* ab = ws_f + 262144;                   // 16 floats
    int* counters = (int*)(ws_f + 262144 + 32);  // 8 ints
    unsigned short* hmask = (unsigned short*)(ws_f + 262144 + 64);

    BlurW kw;
    {
        double g[21], ssum = 0.0;
        for (int i = 0; i < 21; ++i) { double x = (double)(i - 10); g[i] = exp(-x * x / 50.0); ssum += g[i]; }
        for (int i = 0; i < 21; ++i) kw.w[i] = (float)(g[i] / ssum);
    }

    hipMemsetAsync(counters, 0, 8 * sizeof(int), stream);
    produce_kernel<<<1024 + 256, 256, 0, stream>>>(mask, hmask, feat, partial,
                                                   counters, W1, b1, ln_g, ln_b,
                                                   W2, b2, ab, out + NOISY_ELEMS, kw);
    final_kernel<<<512, 256, 0, stream>>>(x_bg, noise, hmask, ab, out, kw);
}

// Round 13
// 123.445 us; speedup vs baseline: 1.2472x; 1.2472x over previous
//
#include <hip/hip_runtime.h>
#include <math.h>

#define B 8
#define C 3
#define H 1024
#define W 1024
#define L 1024
#define D 512
#define DH 128
#define NPIX (H * W)
#define NOISY_ELEMS (B * C * NPIX) // 25165824
#define TH 16                      // rows per strip in final kernel
#define RPB 8                      // rows per block in hblur
#define LROW 1056                  // padded LDS row

typedef float vf2 __attribute__((ext_vector_type(2)));
typedef float vf4 __attribute__((ext_vector_type(4)));
typedef unsigned short us4 __attribute__((ext_vector_type(4)));

struct BlurW { float w[21]; };

static __device__ __forceinline__ unsigned short f2bf(float f) {
    unsigned u = __float_as_uint(f);
    u += 0x7FFFu + ((u >> 16) & 1u);       // round-to-nearest-even
    return (unsigned short)(u >> 16);
}

// ---- kernel A: hblur (bf16 hmask) + colsum + counter-elected head MLP ------
// blocks [0, 1024): 8 mask rows each, staged in LDS, vf4 in, bf16x4 out.
// blocks [1024, 1280): colsum 32 rows of one batch; last block per batch
// (device-scope counter) runs the head MLP inline.
__global__ __launch_bounds__(256) void produce_kernel(
        const float* __restrict__ mask, unsigned short* __restrict__ hmask,
        const float* __restrict__ feat, float* __restrict__ partial,
        int* __restrict__ counters,
        const float* __restrict__ W1, const float* __restrict__ b1,
        const float* __restrict__ ln_g, const float* __restrict__ ln_b,
        const float* __restrict__ W2, const float* __restrict__ b2,
        float* __restrict__ ab, float* __restrict__ out_tail, BlurW kw) {
    int wgid = blockIdx.x;
    int t = threadIdx.x;             // 256

    if (wgid < 1024) {
        __shared__ float Ls[RPB][LROW];  // data at [12..12+W-1], zero halo 10/side
        size_t row0 = (size_t)wgid * RPB;
        const float* src = mask + row0 * W;
        #pragma unroll
        for (int r = 0; r < RPB; ++r) {
            vf4 v = *((const vf4*)(src + (size_t)r * W) + t);
            *(vf4*)&Ls[r][12 + 4 * t] = v;
        }
        if (t < RPB * 10) {
            int r = t / 10, i = t - 10 * r;
            Ls[r][2 + i] = 0.f;
            Ls[r][12 + W + i] = 0.f;
        }
        __syncthreads();
        unsigned short* dst = hmask + row0 * W;
        #pragma unroll
        for (int r = 0; r < RPB; ++r) {
            float v[28];
            #pragma unroll
            for (int j = 0; j < 7; ++j) {
                vf4 q = *(const vf4*)&Ls[r][4 * t + 4 * j];
                v[4 * j] = q.x; v[4 * j + 1] = q.y; v[4 * j + 2] = q.z; v[4 * j + 3] = q.w;
            }
            us4 o;
            #pragma unroll
            for (int i = 0; i < 4; ++i) {
                float acc = 0.f;
                #pragma unroll
                for (int k = 0; k < 10; ++k)
                    acc = fmaf(kw.w[k], v[i + 2 + k] + v[i + 22 - k], acc);
                acc = fmaf(kw.w[10], v[i + 12], acc);
                o[i] = f2bf(acc);
            }
            *(us4*)(dst + (size_t)r * W + 4 * t) = o;   // plain: L2/L3-resident
        }
        return;
    }

    // ---------------- colsum branch ----------------
    int blk = wgid - 1024;           // 0..255
    int b = blk >> 5, chunk = blk & 31;
    int d4 = (t & 127) * 4;
    int half = t >> 7;
    {
        const float* base = feat + (size_t)b * (L * D)
                          + (size_t)(chunk * 32 + half * 16) * D + d4;
        vf4 s = {0.f, 0.f, 0.f, 0.f};
        #pragma unroll
        for (int ll = 0; ll < 16; ++ll) {
            vf4 v = *(const vf4*)(base + (size_t)ll * D);
            s.x += v.x; s.y += v.y; s.z += v.z; s.w += v.w;
        }
        *(vf4*)(partial + ((size_t)(b * 64 + chunk * 2 + half)) * 512 + d4) = s;
    }

    // elect last colsum block of this batch
    __threadfence();                 // release partial write
    __shared__ int winner;
    if (t == 0) winner = (atomicAdd(&counters[b], 1) == 31);
    __syncthreads();
    if (!winner) return;             // block-uniform
    __threadfence();                 // acquire other blocks' partials

    // ---------------- head MLP for batch b (256 threads) ----------------
    __shared__ float fm[D];
    __shared__ float red[DH];
    for (int d = t; d < D; d += 256) {
        float acc = 0.f;
        const float* p = partial + (size_t)b * 64 * 512 + d;
        for (int g = 0; g < 64; ++g) acc += p[g * 512];
        fm[d] = acc * (1.0f / (float)L);
    }
    __syncthreads();
    float h = 0.f;
    if (t < DH) {
        h = b1[t];
        const vf4* fm4 = (const vf4*)fm;
        #pragma unroll 8
        for (int q = 0; q < D / 4; ++q) {
            vf4 f = fm4[q];
            h = fmaf(f.x, W1[(4 * q + 0) * DH + t], h);
            h = fmaf(f.y, W1[(4 * q + 1) * DH + t], h);
            h = fmaf(f.z, W1[(4 * q + 2) * DH + t], h);
            h = fmaf(f.w, W1[(4 * q + 3) * DH + t], h);
        }
    }

    if (t < DH) red[t] = h;
    __syncthreads();
    for (int st = 64; st > 0; st >>= 1) { if (t < st) red[t] += red[t + st]; __syncthreads(); }
    float mu = red[0] * (1.f / (float)DH);
    __syncthreads();
    float hc = h - mu;
    if (t < DH) red[t] = hc * hc;
    __syncthreads();
    for (int st = 64; st > 0; st >>= 1) { if (t < st) red[t] += red[t + st]; __syncthreads(); }
    float var = red[0] * (1.f / (float)DH);
    __syncthreads();

    float hn = 0.f;
    if (t < DH) {
        hn = hc * rsqrtf(var + 1e-5f) * ln_g[t] + ln_b[t];
        hn = fmaxf(hn, 0.f);
    }

    if (t < DH) red[t] = hn * W2[t * 2 + 0];
    __syncthreads();
    for (int st = 64; st > 0; st >>= 1) { if (t < st) red[t] += red[t + st]; __syncthreads(); }
    float p0 = red[0];
    __syncthreads();
    if (t < DH) red[t] = hn * W2[t * 2 + 1];
    __syncthreads();
    for (int st = 64; st > 0; st >>= 1) { if (t < st) red[t] += red[t + st]; __syncthreads(); }
    float p1 = red[0];

    if (t == 0) {
        float a  = 0.00015f / (1.f + expf(-(p0 + b2[0])));
        float be = 0.00015f / (1.f + expf(-(p1 + b2[1])));
        ab[b] = a; ab[8 + b] = be;
        out_tail[b] = a; out_tail[8 + b] = be;
    }
}

// ---------------- kernel B: vertical blur + elementwise synth ---------------
// R10's exact structure: grid B * 64 strips (TH=16) * 2 half-widths = 1024
// blocks, 256 threads, vf2/thread. bf16 window (4B loads) unpacked to f32
// regs; FULLY UNROLLED row loop with %21 static indexing (deep MLP);
// channel-interleaved; plain loads (L3-allocate), nt store only.
__global__ __launch_bounds__(256) void final_kernel(
        const float* __restrict__ x_bg, const float* __restrict__ noise,
        const unsigned short* __restrict__ hmask, const float* __restrict__ ab,
        float* __restrict__ out, BlurW kw) {
    int blk = blockIdx.x;            // 0..1023
    int b   = blk >> 7;              // 128 blocks per batch
    int rem = blk & 127;
    int s   = rem >> 1;              // strip 0..63
    int wj  = rem & 1;
    int h0  = s * TH;
    int t   = threadIdx.x;           // 0..255
    int x0  = wj * 512 + 2 * t;      // column pair base

    const unsigned short* hmb = hmask + (size_t)b * NPIX + x0;
    const vf2 zero2 = {0.f, 0.f};

    vf2 win[21];
    #pragma unroll
    for (int k = 0; k < 21; ++k) {
        int hy = h0 - 10 + k;
        if (hy >= 0 && hy < H) {
            unsigned u = *(const unsigned*)(hmb + (size_t)hy * W);
            win[k].x = __uint_as_float(u << 16);
            win[k].y = __uint_as_float(u & 0xFFFF0000u);
        } else win[k] = zero2;
    }

    float alpha = ab[b], beta = ab[8 + b];

    #pragma unroll
    for (int r = 0; r < TH; ++r) {
        float mx = 0.f, my = 0.f;
        #pragma unroll
        for (int k = 0; k < 10; ++k) {
            float wk = kw.w[k];
            vf2 v1 = win[(r + k) % 21];          // static after unroll
            vf2 v2 = win[(r + 20 - k) % 21];
            mx = fmaf(wk, v1.x + v2.x, mx);
            my = fmaf(wk, v1.y + v2.y, my);
        }
        {
            vf2 vm = win[(r + 10) % 21];
            mx = fmaf(kw.w[10], vm.x, mx);
            my = fmaf(kw.w[10], vm.y, my);
        }
        int h = h0 + r;
        #pragma unroll
        for (int c = 0; c < C; ++c) {
            size_t idx = (((size_t)(b * C + c) * H) + h) * W + x0;
            vf2 x  = *(const vf2*)(x_bg + idx);
            vf2 nz = *(const vf2*)(noise + idx);
            vf2 o;
            float sgx = sqrtf(fmaxf(fmaf(alpha, x.x, beta), 1e-7f));
            float sgy = sqrtf(fmaxf(fmaf(alpha, x.y, beta), 1e-7f));
            o.x = fmaf(1.5f * nz.x * sgx, mx, x.x);
            o.y = fmaf(1.5f * nz.y * sgy, my, x.y);
            __builtin_nontemporal_store(o, (vf2*)(out + idx));
        }
        if (r < TH - 1) {
            int hy = h0 + r + 11;
            int slot = r % 21;                   // static
            if (hy < H) {
                unsigned u = *(const unsigned*)(hmb + (size_t)hy * W);
                win[slot].x = __uint_as_float(u << 16);
                win[slot].y = __uint_as_float(u & 0xFFFF0000u);
            } else win[slot] = zero2;
        }
    }
}

extern "C" void kernel_launch(void* const* d_in, const int* in_sizes, int n_in,
                              void* d_out, int out_size, void* d_ws, size_t ws_size,
                              hipStream_t stream) {
    const float* x_bg = (const float*)d_in[0];
    const float* feat = (const float*)d_in[1];
    const float* mask = (const float*)d_in[2];
    const float* noise = (const float*)d_in[3];
    const float* W1 = (const float*)d_in[4];
    const float* b1 = (const float*)d_in[5];
    const float* ln_g = (const float*)d_in[6];
    const float* ln_b = (const float*)d_in[7];
    const float* W2 = (const float*)d_in[8];
    const float* b2 = (const float*)d_in[9];
    float* out = (float*)d_out;

    // ws layout: [0, 262144) partial colsums (f32) | [262144,+16) ab (f32)
    //            | [+32, +8 ints) counters | hmask bf16 (B*NPIX ushorts)
    float* ws_f = (float*)d_ws;
    float* partial = ws_f;                       // 8*64*512 = 262144 floats
    float* ab = ws_f + 262144;                   // 16 floats
    int* counters = (int*)(ws_f + 262144 + 32);  // 8 ints
    unsigned short* hmask = (unsigned short*)(ws_f + 262144 + 64);

    BlurW kw;
    {
        double g[21], ssum = 0.0;
        for (int i = 0; i < 21; ++i) { double x = (double)(i - 10); g[i] = exp(-x * x / 50.0); ssum += g[i]; }
        for (int i = 0; i < 21; ++i) kw.w[i] = (float)(g[i] / ssum);
    }

    hipMemsetAsync(counters, 0, 8 * sizeof(int), stream);
    produce_kernel<<<1024 + 256, 256, 0, stream>>>(mask, hmask, feat, partial,
                                                   counters, W1, b1, ln_g, ln_b,
                                                   W2, b2, ab, out + NOISY_ELEMS, kw);
    final_kernel<<<1024, 256, 0, stream>>>(x_bg, noise, hmask, ab, out, kw);
}

// Round 14
// 88.789 us; speedup vs baseline: 1.7340x; 1.3903x over previous
//
#include <hip/hip_runtime.h>
#include <math.h>

#define B 8
#define C 3
#define H 1024
#define W 1024
#define L 1024
#define D 512
#define DH 128
#define NPIX (H * W)
#define NOISY_ELEMS (B * C * NPIX) // 25165824
#define TH 16                      // rows per strip in final kernel
#define RPB 8                      // rows per block in hblur
#define LROW 1056                  // padded LDS row

typedef float vf2 __attribute__((ext_vector_type(2)));
typedef float vf4 __attribute__((ext_vector_type(4)));
typedef unsigned short us4 __attribute__((ext_vector_type(4)));

struct BlurW { float w[21]; };

static __device__ __forceinline__ unsigned short f2bf(float f) {
    unsigned u = __float_as_uint(f);
    u += 0x7FFFu + ((u >> 16) & 1u);       // round-to-nearest-even
    return (unsigned short)(u >> 16);
}

// ---------------- kernel 1: fused horizontal blur (bf16 out) + colsum -------
// blocks [0, 1024): 8 mask rows each, staged in LDS, vf4 in, bf16x4 out.
// blocks [1024, 1280): colsum of bottleneck_feat, 32 rows/block, vf4.
// mask/feat loads are NON-TEMPORAL: only this kernel reads them, so don't
// let them occupy L3 — reserve L3 for x/noise/hmask that final re-reads
// every graph replay. hmask store stays plain (L3-allocate).
__global__ __launch_bounds__(256) void hblur_colsum_kernel(
        const float* __restrict__ mask, unsigned short* __restrict__ hmask,
        const float* __restrict__ feat, float* __restrict__ partial, BlurW kw) {
    int wgid = blockIdx.x;
    int t = threadIdx.x;             // 256
    __shared__ float Ls[RPB][LROW];  // data at [12 .. 12+W-1], zero halo 10/side

    if (wgid < 1024) {
        size_t row0 = (size_t)wgid * RPB;
        const float* src = mask + row0 * W;
        #pragma unroll
        for (int r = 0; r < RPB; ++r) {
            vf4 v = __builtin_nontemporal_load((const vf4*)(src + (size_t)r * W) + t);
            *(vf4*)&Ls[r][12 + 4 * t] = v;
        }
        if (t < RPB * 10) {
            int r = t / 10, i = t - 10 * r;
            Ls[r][2 + i] = 0.f;
            Ls[r][12 + W + i] = 0.f;
        }
        __syncthreads();
        unsigned short* dst = hmask + row0 * W;
        #pragma unroll
        for (int r = 0; r < RPB; ++r) {
            float v[28];
            #pragma unroll
            for (int j = 0; j < 7; ++j) {
                vf4 q = *(const vf4*)&Ls[r][4 * t + 4 * j];
                v[4 * j] = q.x; v[4 * j + 1] = q.y; v[4 * j + 2] = q.z; v[4 * j + 3] = q.w;
            }
            us4 o;
            #pragma unroll
            for (int i = 0; i < 4; ++i) {
                float acc = 0.f;
                #pragma unroll
                for (int k = 0; k < 10; ++k)
                    acc = fmaf(kw.w[k], v[i + 2 + k] + v[i + 22 - k], acc);
                acc = fmaf(kw.w[10], v[i + 12], acc);
                o[i] = f2bf(acc);
            }
            *(us4*)(dst + (size_t)r * W + 4 * t) = o;   // plain: L2/L3-resident
        }
    } else {
        int blk = wgid - 1024;       // 0..255
        int b = blk >> 5, chunk = blk & 31;
        int d4 = (t & 127) * 4;
        int half = t >> 7;
        const float* base = feat + (size_t)b * (L * D)
                          + (size_t)(chunk * 32 + half * 16) * D + d4;
        vf4 s = {0.f, 0.f, 0.f, 0.f};
        #pragma unroll
        for (int ll = 0; ll < 16; ++ll) {
            vf4 v = __builtin_nontemporal_load((const vf4*)(base + (size_t)ll * D));
            s.x += v.x; s.y += v.y; s.z += v.z; s.w += v.w;
        }
        float* dst = partial + ((size_t)(b * 64 + chunk * 2 + half)) * 512 + d4;
        *(vf4*)dst = s;
    }
}

// ---------------- kernel 2: MLP head -> alpha/beta --------------------------
__global__ void head_kernel(const float* __restrict__ partial,
                            const float* __restrict__ W1, const float* __restrict__ b1,
                            const float* __restrict__ ln_g, const float* __restrict__ ln_b,
                            const float* __restrict__ W2, const float* __restrict__ b2,
                            float* __restrict__ ab, float* __restrict__ out_tail) {
    const int b = blockIdx.x;
    const int j = threadIdx.x;   // 0..127
    __shared__ float fm[D];
    __shared__ float red[DH];
    for (int d = j; d < D; d += DH) {
        float s = 0.f;
        const float* p = partial + (size_t)b * 64 * D + d;
        for (int c = 0; c < 64; ++c) s += p[c * D];
        fm[d] = s * (1.0f / (float)L);
    }
    __syncthreads();
    float h = b1[j];
    const vf4* fm4 = (const vf4*)fm;
    #pragma unroll 8
    for (int d4 = 0; d4 < D / 4; ++d4) {
        vf4 f = fm4[d4];
        h = fmaf(f.x, W1[(4 * d4 + 0) * DH + j], h);
        h = fmaf(f.y, W1[(4 * d4 + 1) * DH + j], h);
        h = fmaf(f.z, W1[(4 * d4 + 2) * DH + j], h);
        h = fmaf(f.w, W1[(4 * d4 + 3) * DH + j], h);
    }

    red[j] = h; __syncthreads();
    for (int s = 64; s > 0; s >>= 1) { if (j < s) red[j] += red[j + s]; __syncthreads(); }
    float mu = red[0] * (1.f / (float)DH);
    __syncthreads();
    float hc = h - mu;
    red[j] = hc * hc; __syncthreads();
    for (int s = 64; s > 0; s >>= 1) { if (j < s) red[j] += red[j + s]; __syncthreads(); }
    float var = red[0] * (1.f / (float)DH);
    __syncthreads();

    float hn = hc * rsqrtf(var + 1e-5f) * ln_g[j] + ln_b[j];
    hn = fmaxf(hn, 0.f);

    red[j] = hn * W2[j * 2 + 0]; __syncthreads();
    for (int s = 64; s > 0; s >>= 1) { if (j < s) red[j] += red[j + s]; __syncthreads(); }
    float p0 = red[0];
    __syncthreads();
    red[j] = hn * W2[j * 2 + 1]; __syncthreads();
    for (int s = 64; s > 0; s >>= 1) { if (j < s) red[j] += red[j + s]; __syncthreads(); }
    float p1 = red[0];

    if (j == 0) {
        float a  = 0.00015f / (1.f + expf(-(p0 + b2[0])));
        float be = 0.00015f / (1.f + expf(-(p1 + b2[1])));
        ab[b] = a; ab[8 + b] = be;
        out_tail[b] = a; out_tail[8 + b] = be;
    }
}

// ---------------- kernel 3: vertical blur + elementwise synth ---------------
// R10's exact structure: grid B * 64 strips (TH=16) * 2 half-widths = 1024
// blocks, 256 threads, vf2/thread. bf16 window (4B loads) unpacked to f32
// regs; fully unrolled row loop, %21 static indexing; channel-interleaved;
// plain loads (L3-allocate; replays hit), nt store only (out never re-read).
__global__ __launch_bounds__(256) void final_kernel(
        const float* __restrict__ x_bg, const float* __restrict__ noise,
        const unsigned short* __restrict__ hmask, const float* __restrict__ ab,
        float* __restrict__ out, BlurW kw) {
    int blk = blockIdx.x;            // 0..1023
    int b   = blk >> 7;              // 128 blocks per batch
    int rem = blk & 127;
    int s   = rem >> 1;              // strip 0..63
    int wj  = rem & 1;
    int h0  = s * TH;
    int t   = threadIdx.x;           // 0..255
    int x0  = wj * 512 + 2 * t;      // column pair base

    const unsigned short* hmb = hmask + (size_t)b * NPIX + x0;
    const vf2 zero2 = {0.f, 0.f};

    vf2 win[21];
    #pragma unroll
    for (int k = 0; k < 21; ++k) {
        int hy = h0 - 10 + k;
        if (hy >= 0 && hy < H) {
            unsigned u = *(const unsigned*)(hmb + (size_t)hy * W);
            win[k].x = __uint_as_float(u << 16);
            win[k].y = __uint_as_float(u & 0xFFFF0000u);
        } else win[k] = zero2;
    }

    float alpha = ab[b], beta = ab[8 + b];

    #pragma unroll
    for (int r = 0; r < TH; ++r) {
        float mx = 0.f, my = 0.f;
        #pragma unroll
        for (int k = 0; k < 10; ++k) {
            float wk = kw.w[k];
            vf2 v1 = win[(r + k) % 21];          // static after unroll
            vf2 v2 = win[(r + 20 - k) % 21];
            mx = fmaf(wk, v1.x + v2.x, mx);
            my = fmaf(wk, v1.y + v2.y, my);
        }
        {
            vf2 vm = win[(r + 10) % 21];
            mx = fmaf(kw.w[10], vm.x, mx);
            my = fmaf(kw.w[10], vm.y, my);
        }
        int h = h0 + r;
        #pragma unroll
        for (int c = 0; c < C; ++c) {
            size_t idx = (((size_t)(b * C + c) * H) + h) * W + x0;
            vf2 x  = *(const vf2*)(x_bg + idx);
            vf2 nz = *(const vf2*)(noise + idx);
            vf2 o;
            float sgx = sqrtf(fmaxf(fmaf(alpha, x.x, beta), 1e-7f));
            float sgy = sqrtf(fmaxf(fmaf(alpha, x.y, beta), 1e-7f));
            o.x = fmaf(1.5f * nz.x * sgx, mx, x.x);
            o.y = fmaf(1.5f * nz.y * sgy, my, x.y);
            __builtin_nontemporal_store(o, (vf2*)(out + idx));
        }
        if (r < TH - 1) {
            int hy = h0 + r + 11;
            int slot = r % 21;                   // static
            if (hy < H) {
                unsigned u = *(const unsigned*)(hmb + (size_t)hy * W);
                win[slot].x = __uint_as_float(u << 16);
                win[slot].y = __uint_as_float(u & 0xFFFF0000u);
            } else win[slot] = zero2;
        }
    }
}

extern "C" void kernel_launch(void* const* d_in, const int* in_sizes, int n_in,
                              void* d_out, int out_size, void* d_ws, size_t ws_size,
                              hipStream_t stream) {
    const float* x_bg = (const float*)d_in[0];
    const float* feat = (const float*)d_in[1];
    const float* mask = (const float*)d_in[2];
    const float* noise = (const float*)d_in[3];
    const float* W1 = (const float*)d_in[4];
    const float* b1 = (const float*)d_in[5];
    const float* ln_g = (const float*)d_in[6];
    const float* ln_b = (const float*)d_in[7];
    const float* W2 = (const float*)d_in[8];
    const float* b2 = (const float*)d_in[9];
    float* out = (float*)d_out;

    // ws layout: [0, 262144) partial colsums (f32) | [262144, +16) ab (f32)
    //            | hmask as bf16 (B*NPIX ushorts)
    float* ws_f = (float*)d_ws;
    float* partial = ws_f;                       // 8*64*512 = 262144 floats
    float* ab = ws_f + 262144;                   // 16 floats
    unsigned short* hmask = (unsigned short*)(ws_f + 262144 + 64);

    BlurW kw;
    {
        double g[21], ssum = 0.0;
        for (int i = 0; i < 21; ++i) { double x = (double)(i - 10); g[i] = exp(-x * x / 50.0); ssum += g[i]; }
        for (int i = 0; i < 21; ++i) kw.w[i] = (float)(g[i] / ssum);
    }

    hblur_colsum_kernel<<<1024 + 256, 256, 0, stream>>>(mask, hmask, feat, partial, kw);
    head_kernel<<<B, 128, 0, stream>>>(partial, W1, b1, ln_g, ln_b, W2, b2,
                                       ab, out + NOISY_ELEMS);
    final_kernel<<<1024, 256, 0, stream>>>(x_bg, noise, hmask, ab, out, kw);
}

// Round 15
// 87.478 us; speedup vs baseline: 1.7600x; 1.0150x over previous
//
#include <hip/hip_runtime.h>
#include <math.h>

#define B 8
#define C 3
#define H 1024
#define W 1024
#define L 1024
#define D 512
#define DH 128
#define NPIX (H * W)
#define NOISY_ELEMS (B * C * NPIX) // 25165824
#define TH 16                      // rows per strip in final kernel
#define RPB 8                      // rows per block in hblur
#define LROW 1056                  // padded LDS row

typedef float vf2 __attribute__((ext_vector_type(2)));
typedef float vf4 __attribute__((ext_vector_type(4)));
typedef unsigned short us4 __attribute__((ext_vector_type(4)));

struct BlurW { float w[21]; };

static __device__ __forceinline__ unsigned short f2bf(float f) {
    unsigned u = __float_as_uint(f);
    u += 0x7FFFu + ((u >> 16) & 1u);       // round-to-nearest-even
    return (unsigned short)(u >> 16);
}

// ---------------- kernel 1: fused horizontal blur (bf16 out) + colsum -------
// blocks [0, 1024): 8 mask rows each, staged in LDS, vf4 in, bf16x4 out.
// blocks [1024, 1280): colsum of bottleneck_feat, 32 rows/block, vf4.
// mask loads PLAIN (L3-resident across replays: 251.7 MB total set fits);
// feat loads NON-TEMPORAL (would overflow L3; only read once per call).
__global__ __launch_bounds__(256) void hblur_colsum_kernel(
        const float* __restrict__ mask, unsigned short* __restrict__ hmask,
        const float* __restrict__ feat, float* __restrict__ partial, BlurW kw) {
    int wgid = blockIdx.x;
    int t = threadIdx.x;             // 256
    __shared__ float Ls[RPB][LROW];  // data at [12 .. 12+W-1], zero halo 10/side

    if (wgid < 1024) {
        size_t row0 = (size_t)wgid * RPB;
        const float* src = mask + row0 * W;
        #pragma unroll
        for (int r = 0; r < RPB; ++r) {
            vf4 v = *((const vf4*)(src + (size_t)r * W) + t);   // plain: L3-allocate
            *(vf4*)&Ls[r][12 + 4 * t] = v;
        }
        if (t < RPB * 10) {
            int r = t / 10, i = t - 10 * r;
            Ls[r][2 + i] = 0.f;
            Ls[r][12 + W + i] = 0.f;
        }
        __syncthreads();
        unsigned short* dst = hmask + row0 * W;
        #pragma unroll
        for (int r = 0; r < RPB; ++r) {
            float v[28];
            #pragma unroll
            for (int j = 0; j < 7; ++j) {
                vf4 q = *(const vf4*)&Ls[r][4 * t + 4 * j];
                v[4 * j] = q.x; v[4 * j + 1] = q.y; v[4 * j + 2] = q.z; v[4 * j + 3] = q.w;
            }
            us4 o;
            #pragma unroll
            for (int i = 0; i < 4; ++i) {
                float acc = 0.f;
                #pragma unroll
                for (int k = 0; k < 10; ++k)
                    acc = fmaf(kw.w[k], v[i + 2 + k] + v[i + 22 - k], acc);
                acc = fmaf(kw.w[10], v[i + 12], acc);
                o[i] = f2bf(acc);
            }
            *(us4*)(dst + (size_t)r * W + 4 * t) = o;   // plain: L2/L3-resident
        }
    } else {
        int blk = wgid - 1024;       // 0..255
        int b = blk >> 5, chunk = blk & 31;
        int d4 = (t & 127) * 4;
        int half = t >> 7;
        const float* base = feat + (size_t)b * (L * D)
                          + (size_t)(chunk * 32 + half * 16) * D + d4;
        vf4 s = {0.f, 0.f, 0.f, 0.f};
        #pragma unroll
        for (int ll = 0; ll < 16; ++ll) {
            vf4 v = __builtin_nontemporal_load((const vf4*)(base + (size_t)ll * D));
            s.x += v.x; s.y += v.y; s.z += v.z; s.w += v.w;
        }
        float* dst = partial + ((size_t)(b * 64 + chunk * 2 + half)) * 512 + d4;
        *(vf4*)dst = s;
    }
}

// ---------------- kernel 2: MLP head -> alpha/beta --------------------------
__global__ void head_kernel(const float* __restrict__ partial,
                            const float* __restrict__ W1, const float* __restrict__ b1,
                            const float* __restrict__ ln_g, const float* __restrict__ ln_b,
                            const float* __restrict__ W2, const float* __restrict__ b2,
                            float* __restrict__ ab, float* __restrict__ out_tail) {
    const int b = blockIdx.x;
    const int j = threadIdx.x;   // 0..127
    __shared__ float fm[D];
    __shared__ float red[DH];
    for (int d = j; d < D; d += DH) {
        float s = 0.f;
        const float* p = partial + (size_t)b * 64 * D + d;
        for (int c = 0; c < 64; ++c) s += p[c * D];
        fm[d] = s * (1.0f / (float)L);
    }
    __syncthreads();
    float h = b1[j];
    const vf4* fm4 = (const vf4*)fm;
    #pragma unroll 8
    for (int d4 = 0; d4 < D / 4; ++d4) {
        vf4 f = fm4[d4];
        h = fmaf(f.x, W1[(4 * d4 + 0) * DH + j], h);
        h = fmaf(f.y, W1[(4 * d4 + 1) * DH + j], h);
        h = fmaf(f.z, W1[(4 * d4 + 2) * DH + j], h);
        h = fmaf(f.w, W1[(4 * d4 + 3) * DH + j], h);
    }

    red[j] = h; __syncthreads();
    for (int s = 64; s > 0; s >>= 1) { if (j < s) red[j] += red[j + s]; __syncthreads(); }
    float mu = red[0] * (1.f / (float)DH);
    __syncthreads();
    float hc = h - mu;
    red[j] = hc * hc; __syncthreads();
    for (int s = 64; s > 0; s >>= 1) { if (j < s) red[j] += red[j + s]; __syncthreads(); }
    float var = red[0] * (1.f / (float)DH);
    __syncthreads();

    float hn = hc * rsqrtf(var + 1e-5f) * ln_g[j] + ln_b[j];
    hn = fmaxf(hn, 0.f);

    red[j] = hn * W2[j * 2 + 0]; __syncthreads();
    for (int s = 64; s > 0; s >>= 1) { if (j < s) red[j] += red[j + s]; __syncthreads(); }
    float p0 = red[0];
    __syncthreads();
    red[j] = hn * W2[j * 2 + 1]; __syncthreads();
    for (int s = 64; s > 0; s >>= 1) { if (j < s) red[j] += red[j + s]; __syncthreads(); }
    float p1 = red[0];

    if (j == 0) {
        float a  = 0.00015f / (1.f + expf(-(p0 + b2[0])));
        float be = 0.00015f / (1.f + expf(-(p1 + b2[1])));
        ab[b] = a; ab[8 + b] = be;
        out_tail[b] = a; out_tail[8 + b] = be;
    }
}

// ---------------- kernel 3: vertical blur + elementwise synth ---------------
// R10's exact structure: grid B * 64 strips (TH=16) * 2 half-widths = 1024
// blocks, 256 threads, vf2/thread. bf16 window (4B loads) unpacked to f32
// regs; fully unrolled row loop, %21 static indexing; channel-interleaved;
// plain loads (L3-allocate; replays hit), nt store only (out never re-read).
__global__ __launch_bounds__(256) void final_kernel(
        const float* __restrict__ x_bg, const float* __restrict__ noise,
        const unsigned short* __restrict__ hmask, const float* __restrict__ ab,
        float* __restrict__ out, BlurW kw) {
    int blk = blockIdx.x;            // 0..1023
    int b   = blk >> 7;              // 128 blocks per batch
    int rem = blk & 127;
    int s   = rem >> 1;              // strip 0..63
    int wj  = rem & 1;
    int h0  = s * TH;
    int t   = threadIdx.x;           // 0..255
    int x0  = wj * 512 + 2 * t;      // column pair base

    const unsigned short* hmb = hmask + (size_t)b * NPIX + x0;
    const vf2 zero2 = {0.f, 0.f};

    vf2 win[21];
    #pragma unroll
    for (int k = 0; k < 21; ++k) {
        int hy = h0 - 10 + k;
        if (hy >= 0 && hy < H) {
            unsigned u = *(const unsigned*)(hmb + (size_t)hy * W);
            win[k].x = __uint_as_float(u << 16);
            win[k].y = __uint_as_float(u & 0xFFFF0000u);
        } else win[k] = zero2;
    }

    float alpha = ab[b], beta = ab[8 + b];

    #pragma unroll
    for (int r = 0; r < TH; ++r) {
        float mx = 0.f, my = 0.f;
        #pragma unroll
        for (int k = 0; k < 10; ++k) {
            float wk = kw.w[k];
            vf2 v1 = win[(r + k) % 21];          // static after unroll
            vf2 v2 = win[(r + 20 - k) % 21];
            mx = fmaf(wk, v1.x + v2.x, mx);
            my = fmaf(wk, v1.y + v2.y, my);
        }
        {
            vf2 vm = win[(r + 10) % 21];
            mx = fmaf(kw.w[10], vm.x, mx);
            my = fmaf(kw.w[10], vm.y, my);
        }
        int h = h0 + r;
        #pragma unroll
        for (int c = 0; c < C; ++c) {
            size_t idx = (((size_t)(b * C + c) * H) + h) * W + x0;
            vf2 x  = *(const vf2*)(x_bg + idx);
            vf2 nz = *(const vf2*)(noise + idx);
            vf2 o;
            float sgx = sqrtf(fmaxf(fmaf(alpha, x.x, beta), 1e-7f));
            float sgy = sqrtf(fmaxf(fmaf(alpha, x.y, beta), 1e-7f));
            o.x = fmaf(1.5f * nz.x * sgx, mx, x.x);
            o.y = fmaf(1.5f * nz.y * sgy, my, x.y);
            __builtin_nontemporal_store(o, (vf2*)(out + idx));
        }
        if (r < TH - 1) {
            int hy = h0 + r + 11;
            int slot = r % 21;                   // static
            if (hy < H) {
                unsigned u = *(const unsigned*)(hmb + (size_t)hy * W);
                win[slot].x = __uint_as_float(u << 16);
                win[slot].y = __uint_as_float(u & 0xFFFF0000u);
            } else win[slot] = zero2;
        }
    }
}

extern "C" void kernel_launch(void* const* d_in, const int* in_sizes, int n_in,
                              void* d_out, int out_size, void* d_ws, size_t ws_size,
                              hipStream_t stream) {
    const float* x_bg = (const float*)d_in[0];
    const float* feat = (const float*)d_in[1];
    const float* mask = (const float*)d_in[2];
    const float* noise = (const float*)d_in[3];
    const float* W1 = (const float*)d_in[4];
    const float* b1 = (const float*)d_in[5];
    const float* ln_g = (const float*)d_in[6];
    const float* ln_b = (const float*)d_in[7];
    const float* W2 = (const float*)d_in[8];
    const float* b2 = (const float*)d_in[9];
    float* out = (float*)d_out;

    // ws layout: [0, 262144) partial colsums (f32) | [262144, +16) ab (f32)
    //            | hmask as bf16 (B*NPIX ushorts)
    float* ws_f = (float*)d_ws;
    float* partial = ws_f;                       // 8*64*512 = 262144 floats
    float* ab = ws_f + 262144;                   // 16 floats
    unsigned short* hmask = (unsigned short*)(ws_f + 262144 + 64);

    BlurW kw;
    {
        double g[21], ssum = 0.0;
        for (int i = 0; i < 21; ++i) { double x = (double)(i - 10); g[i] = exp(-x * x / 50.0); ssum += g[i]; }
        for (int i = 0; i < 21; ++i) kw.w[i] = (float)(g[i] / ssum);
    }

    hblur_colsum_kernel<<<1024 + 256, 256, 0, stream>>>(mask, hmask, feat, partial, kw);
    head_kernel<<<B, 128, 0, stream>>>(partial, W1, b1, ln_g, ln_b, W2, b2,
                                       ab, out + NOISY_ELEMS);
    final_kernel<<<1024, 256, 0, stream>>>(x_bg, noise, hmask, ab, out, kw);
}